// Round 10
// baseline (202.907 us; speedup 1.0000x reference)
//
#include <hip/hip_runtime.h>
#include <stdint.h>

#define N_NODES 50000
#define N_EDGES 800000
#define IN_F 128
#define HID_F 128
#define OUT_F 128
#define CAT_F 256

#define NB 200     // scatter partition blocks (200*4000 = 800000 exact)
#define CHUNK 4000 // edges per partition (divisible by 4)
#define NREG 196   // coarse regions of 256 nodes (ceil(50000/256))
#define RCAP 4608  // region record capacity (mean 4096, sigma 64, +8 sigma)
#define NBUCK 3125 // fine buckets of 16 nodes (50000/16 exact)
#define BCAP 416   // per-fine-bucket srec capacity (mean 256, +10 sigma)

typedef __bf16 bf16x8 __attribute__((ext_vector_type(8)));
typedef float f32x4 __attribute__((ext_vector_type(4)));

__device__ __forceinline__ uint32_t f2b(float f) {
  uint32_t u = __float_as_uint(f);
  return (u + 0x7fffu + ((u >> 16) & 1u)) >> 16;  // RNE
}

// ---- K1: fused  [0,NB): coarse sort+scatter (COALESCED writes) | [NB,..):
// h/Qw/Ww -> bf16 convert.
// R9: R8's fine scatter wrote random 8B records (64B-line amplification ~7x,
// ~38MB). Here each block LDS-sorts its 4000 edges by coarse region (196
// regions of 256 nodes), bulk-allocates region space (196 independent
// returning atomics, proven R8 Phase-B pattern), then flushes SORTED runs:
// consecutive threads -> consecutive global addresses (avg run 20 rec = 163B).
// Record: x = src(16b) | node-in-region(8b)<<16 | region(8b)<<24 ; y = weight.
__global__ void __launch_bounds__(256) prep_scatter_kernel(
    const int* __restrict__ dst, const int* __restrict__ src, const float* __restrict__ ppr,
    int* __restrict__ gcnt, int2* __restrict__ recG, const float* __restrict__ h,
    const float* __restrict__ Qw, const float* __restrict__ Ww, uint16_t* __restrict__ hB,
    uint16_t* __restrict__ QwB, uint16_t* __restrict__ WwB) {
  if (blockIdx.x < NB) {
    __shared__ int2 srt[CHUNK];   // 32 KB
    __shared__ int lhist[NREG];
    __shared__ int lbase[NREG];
    __shared__ int adjrel[NREG];  // (global alloc base - local base)
    __shared__ int lcur[NREG];
    int t = threadIdx.x;
    int g0 = blockIdx.x * (CHUNK / 4);  // first int4 group
    // Phase A: histogram by region
    for (int k = t; k < NREG; k += 256) lhist[k] = 0;
    __syncthreads();
    for (int i4 = g0 + t; i4 < g0 + CHUNK / 4; i4 += 256) {
      int4 d4 = ((const int4*)dst)[i4];
      atomicAdd(&lhist[((unsigned)d4.x) >> 8], 1);
      atomicAdd(&lhist[((unsigned)d4.y) >> 8], 1);
      atomicAdd(&lhist[((unsigned)d4.z) >> 8], 1);
      atomicAdd(&lhist[((unsigned)d4.w) >> 8], 1);
    }
    __syncthreads();
    // Phase B1: exclusive scan of 196 counters (wave 0, 4/lane)
    if (t < 64) {
      int c4[4], l4[4];
      int s = 0;
#pragma unroll
      for (int j = 0; j < 4; ++j) {
        int idx = t * 4 + j;
        c4[j] = (idx < NREG) ? lhist[idx] : 0;
        l4[j] = s;
        s += c4[j];
      }
      int inc = s;
#pragma unroll
      for (int d = 1; d < 64; d <<= 1) {
        int x = __shfl_up(inc, d, 64);
        if (t >= d) inc += x;
      }
      int exc = inc - s;
#pragma unroll
      for (int j = 0; j < 4; ++j) {
        int idx = t * 4 + j;
        if (idx < NREG) lbase[idx] = exc + l4[j];
      }
    }
    __syncthreads();
    // Phase B2: bulk-allocate region space (independent returning atomics)
    for (int k = t; k < NREG; k += 256) {
      int hv = lhist[k];
      int gb = hv ? atomicAdd(&gcnt[k], hv) : 0;
      adjrel[k] = gb - lbase[k];
      lcur[k] = lbase[k];
    }
    __syncthreads();
    // Phase C: LDS-sort records by region
    for (int i4 = g0 + t; i4 < g0 + CHUNK / 4; i4 += 256) {
      int4 d4 = ((const int4*)dst)[i4];
      int4 s4 = ((const int4*)src)[i4];
      float4 w4 = ((const float4*)ppr)[i4];
#define PUT(D, S, W)                                                          \
  {                                                                           \
    unsigned d = (unsigned)(D);                                               \
    int k = d >> 8;                                                           \
    int p = atomicAdd(&lcur[k], 1);                                           \
    srt[p] = make_int2(                                                       \
        (int)((unsigned)(S) | ((d & 255u) << 16) | ((unsigned)k << 24)),      \
        __float_as_int(W));                                                   \
  }
      PUT(d4.x, s4.x, w4.x);
      PUT(d4.y, s4.y, w4.y);
      PUT(d4.z, s4.z, w4.z);
      PUT(d4.w, s4.w, w4.w);
#undef PUT
    }
    __syncthreads();
    // Phase D: coalesced flush of sorted runs
    for (int p = t; p < CHUNK; p += 256) {
      int2 rc = srt[p];
      int k = ((unsigned)rc.x) >> 24;
      int pr = adjrel[k] + p;  // = gb + (p - lbase[k])
      if (pr < RCAP) recG[(size_t)k * RCAP + pr] = rc;
    }
  } else {
    const int TOT4 = (N_NODES * IN_F + HID_F * IN_F + OUT_F * CAT_F) / 4;  // 1612288
    int i4 = (blockIdx.x - NB) * 256 + threadIdx.x;
    if (i4 >= TOT4) return;
    int base = i4 * 4;
    const float* srcp;
    uint16_t* dstp;
    int off;
    if (base < N_NODES * IN_F) {
      srcp = h; dstp = hB; off = base;
    } else if (base < N_NODES * IN_F + HID_F * IN_F) {
      srcp = Qw; dstp = QwB; off = base - N_NODES * IN_F;
    } else {
      srcp = Ww; dstp = WwB; off = base - N_NODES * IN_F - HID_F * IN_F;
    }
    float4 v = *(const float4*)(srcp + off);
    ushort4 o;
    o.x = (uint16_t)f2b(v.x); o.y = (uint16_t)f2b(v.y);
    o.z = (uint16_t)f2b(v.z); o.w = (uint16_t)f2b(v.w);
    *(ushort4*)(dstp + off) = o;
  }
}

// ---- K2: aggregation ONLY (no MFMA phases -> protects P4's regalloc; R3
// measured 2.25 TB/s gather in exactly this register context, while R5/R6/R8
// showed in-kernel MFMA phases clamp VGPR and re-serialize the ping-pong).
// Block g owns fine bucket g (16 nodes). It streams its parent region
// (r = g>>4, ~4.6K records, coalesced + L2-shared with 15 sibling blocks),
// filters for its 16 nodes, LDS-sorts them, then runs R3's 2-deep ping-pong
// gather. Output: hagg (bf16) + wsum (f32) to global.
__global__ void __launch_bounds__(256) agg_kernel(
    const int2* __restrict__ recG, const int* __restrict__ gcnt,
    const uint16_t* __restrict__ hB, uint16_t* __restrict__ haggB,
    float* __restrict__ wsumG) {
  __shared__ int2 srec[BCAP];  // 3.3 KB
  __shared__ int hist[16];
  __shared__ int noff[17];
  __shared__ int cur[16];
  int g = blockIdx.x;
  int t = threadIdx.x;
  int r = g >> 4, myf = g & 15;
  if (t < 16) hist[t] = 0;
  __syncthreads();

  int rlen = gcnt[r];
  rlen = (rlen < RCAP) ? rlen : RCAP;
  const int2* rb = recG + (size_t)r * RCAP;

  // P1: stream region, filter to this fine bucket, histogram by node
  for (int i = t; i < rlen; i += 256) {
    int x = rb[i].x;
    if (((x >> 20) & 15) == myf) atomicAdd(&hist[(x >> 16) & 15], 1);
  }
  __syncthreads();

  // P2: exclusive scan of 16 counters (lanes 0..15 of wave 0)
  if (t < 16) {
    int v = hist[t];
    int inc = v;
#pragma unroll
    for (int d = 1; d < 16; d <<= 1) {
      int x = __shfl_up(inc, d, 64);
      if (t >= d) inc += x;
    }
    noff[t] = inc - v;
    cur[t] = inc - v;
    if (t == 15) noff[16] = inc;
  }
  __syncthreads();

  // P3: second streaming pass (L2-hot), scatter matches node-sorted into LDS
  for (int i = t; i < rlen; i += 256) {
    int2 rc = rb[i];
    if (((rc.x >> 20) & 15) == myf) {
      int p = atomicAdd(&cur[(rc.x >> 16) & 15], 1);
      if (p < BCAP) srec[p] = rc;
    }
  }
  __syncthreads();

  // P4: sub-as-node aggregation with 2-deep ping-pong prefetch (R3 verbatim,
  // src mask 0xFFFF). 16 subs of 16 lanes; each sub owns 1 node.
  {
    int gs = t >> 4, c = t & 15;
    const uint4* hb4 = (const uint4*)hB;
    int nl = gs;
    int nbeg = noff[nl], nend = noff[nl + 1];
    nbeg = (nbeg < BCAP) ? nbeg : BCAP;
    nend = (nend < BCAP) ? nend : BCAP;
    int last = nend - 1;
    float a[8];
#pragma unroll
    for (int j = 0; j < 8; ++j) a[j] = 0.f;
    float ws = 0.f;

    int2 rrA[4], rrB[4];
    uint4 uA[4], uB[4];

#define LOADB(E0, RR, UU)                                         \
  {                                                               \
    _Pragma("unroll") for (int j = 0; j < 4; ++j) {               \
      int i = (E0) + j;                                           \
      RR[j] = srec[(i < last) ? i : last];                        \
    }                                                             \
    _Pragma("unroll") for (int j = 0; j < 4; ++j)                 \
        UU[j] = hb4[(size_t)(RR[j].x & 0xFFFF) * 16 + c];         \
  }

#define CONSB(E0, RR, UU)                                           \
  {                                                                 \
    _Pragma("unroll") for (int j = 0; j < 4; ++j) {                 \
      float w = ((E0) + j < nend) ? __int_as_float(RR[j].y) : 0.f;  \
      ws += w;                                                      \
      uint32_t x;                                                   \
      x = UU[j].x;                                                  \
      a[0] += w * __uint_as_float(x << 16);                         \
      a[1] += w * __uint_as_float(x & 0xffff0000u);                 \
      x = UU[j].y;                                                  \
      a[2] += w * __uint_as_float(x << 16);                         \
      a[3] += w * __uint_as_float(x & 0xffff0000u);                 \
      x = UU[j].z;                                                  \
      a[4] += w * __uint_as_float(x << 16);                         \
      a[5] += w * __uint_as_float(x & 0xffff0000u);                 \
      x = UU[j].w;                                                  \
      a[6] += w * __uint_as_float(x << 16);                         \
      a[7] += w * __uint_as_float(x & 0xffff0000u);                 \
    }                                                               \
  }

    int e = nbeg;
    if (e < nend) {
      LOADB(e, rrA, uA);
      while (true) {
        int eB = e + 4;
        if (eB < nend) {
          LOADB(eB, rrB, uB);  // B in flight while A consumed
          CONSB(e, rrA, uA);
          int eA = eB + 4;
          if (eA < nend) {
            LOADB(eA, rrA, uA);  // A in flight while B consumed
            CONSB(eB, rrB, uB);
            e = eA;
          } else {
            CONSB(eB, rrB, uB);
            break;
          }
        } else {
          CONSB(e, rrA, uA);
          break;
        }
      }
    }
#undef LOADB
#undef CONSB

    float dnm = (ws == 0.f) ? 1.f : ws;  // safediv
    float inv = 1.f / dnm;
    uint4 o;
    o.x = f2b(a[0] * inv) | (f2b(a[1] * inv) << 16);
    o.y = f2b(a[2] * inv) | (f2b(a[3] * inv) << 16);
    o.z = f2b(a[4] * inv) | (f2b(a[5] * inv) << 16);
    o.w = f2b(a[6] * inv) | (f2b(a[7] * inv) << 16);
    int node = g * 16 + nl;
    ((uint4*)haggB)[(size_t)node * 16 + c] = o;
    if (c == 0) wsumG[node] = ws;
  }
}

// ---- K3: Q + GEMM2, dense MFMA kernel. One wave per 16-row strip (4/block).
// hq2 = hagg @ Qw^T + Qb (Qb gated by wsum!=0); out = L2norm(leaky([hB|hq2] @
// Ww^T + Wb)). Q-output goes through LDS to convert C-layout -> A-fragments
// (R5's proven pattern).
__global__ void __launch_bounds__(256) qgemm2_kernel(
    const uint16_t* __restrict__ haggB, const float* __restrict__ wsumG,
    const uint16_t* __restrict__ hB, const uint16_t* __restrict__ QwB,
    const float* __restrict__ Qb, const uint16_t* __restrict__ WwB,
    const float* __restrict__ Wb, float* __restrict__ out) {
  __shared__ uint4 hq2[4][16][17];  // 17.4 KB (pad breaks stride conflicts)
  int t = threadIdx.x;
  int wv = t >> 6, lane = t & 63;
  int w = blockIdx.x * 4 + wv;
  bool act = (w < NBUCK);  // inactive waves still hit the barrier
  int row0 = act ? w * 16 : 0;
  int rl = lane & 15, qd = lane >> 4;

  if (act) {
    // Q phase: accq[tt] covers output cols tt*16.., rows qd*4+j
    f32x4 accq[8];
#pragma unroll
    for (int tt = 0; tt < 8; ++tt) accq[tt] = (f32x4){0.f, 0.f, 0.f, 0.f};
    const uint16_t* aRow = haggB + (size_t)(row0 + rl) * HID_F + qd * 8;
#pragma unroll
    for (int kt = 0; kt < 4; ++kt) {
      bf16x8 a = *(const bf16x8*)(aRow + kt * 32);
#pragma unroll
      for (int tt = 0; tt < 8; ++tt) {
        bf16x8 b = *(const bf16x8*)(QwB + (tt * 16 + rl) * IN_F + kt * 32 + qd * 8);
        accq[tt] = __builtin_amdgcn_mfma_f32_16x16x32_bf16(a, b, accq[tt], 0, 0, 0);
      }
    }
    float fl[4];
#pragma unroll
    for (int j = 0; j < 4; ++j)
      fl[j] = (wsumG[row0 + qd * 4 + j] != 0.f) ? 1.f : 0.f;
#pragma unroll
    for (int tt = 0; tt < 8; ++tt) {
      float qb = Qb[tt * 16 + rl];
#pragma unroll
      for (int j = 0; j < 4; ++j) {
        int row = qd * 4 + j;
        ((uint16_t*)&hq2[wv][row][0])[tt * 16 + rl] =
            (uint16_t)f2b(accq[tt][j] + qb * fl[j]);
      }
    }
  }
  __syncthreads();
  if (!act) return;  // no barriers below

  // GEMM2 (R3 P5 structure)
  f32x4 acc2[8];
#pragma unroll
  for (int tt = 0; tt < 8; ++tt) acc2[tt] = (f32x4){0.f, 0.f, 0.f, 0.f};
  const uint16_t* aRow2 = hB + (size_t)(row0 + rl) * IN_F + qd * 8;
#pragma unroll
  for (int kt = 0; kt < 8; ++kt) {
    bf16x8 av;
    if (kt < 4) {
      av = *(const bf16x8*)(aRow2 + kt * 32);
    } else {
      av = *(const bf16x8*)&hq2[wv][rl][(kt - 4) * 4 + qd];
    }
#pragma unroll
    for (int tt = 0; tt < 8; ++tt) {
      bf16x8 b = *(const bf16x8*)(WwB + (tt * 16 + rl) * CAT_F + kt * 32 + qd * 8);
      acc2[tt] = __builtin_amdgcn_mfma_f32_16x16x32_bf16(av, b, acc2[tt], 0, 0, 0);
    }
  }
  float lv[8][4];
  float ss[4] = {0.f, 0.f, 0.f, 0.f};
#pragma unroll
  for (int tt = 0; tt < 8; ++tt) {
    float wb = Wb[tt * 16 + rl];
#pragma unroll
    for (int j = 0; j < 4; ++j) {
      float v = acc2[tt][j] + wb;
      v = (v >= 0.f) ? v : 0.01f * v;
      lv[tt][j] = v;
      ss[j] += v * v;
    }
  }
#pragma unroll
  for (int j = 0; j < 4; ++j) {
    float s = ss[j];
    s += __shfl_xor(s, 1);
    s += __shfl_xor(s, 2);
    s += __shfl_xor(s, 4);
    s += __shfl_xor(s, 8);
    float nr = sqrtf(s);
    float inv = (nr == 0.f) ? 1.f : (1.f / nr);
    int mrow = row0 + qd * 4 + j;
    float* orow = out + (size_t)mrow * OUT_F;
#pragma unroll
    for (int tt = 0; tt < 8; ++tt) orow[tt * 16 + rl] = lv[tt][j] * inv;
  }
}

extern "C" void kernel_launch(void* const* d_in, const int* in_sizes, int n_in,
                              void* d_out, int out_size, void* d_ws, size_t ws_size,
                              hipStream_t stream) {
  const float* h = (const float*)d_in[0];
  const float* ppr = (const float*)d_in[1];
  const float* Qw = (const float*)d_in[2];
  const float* Qb = (const float*)d_in[3];
  const float* Ww = (const float*)d_in[4];
  const float* Wb = (const float*)d_in[5];
  const int* src = (const int*)d_in[6];
  const int* dst = (const int*)d_in[7];
  float* out = (float*)d_out;

  char* ws = (char*)d_ws;
  size_t o = 0;
  auto alloc = [&](size_t bytes) {
    void* p = ws + o;
    o = (o + bytes + 255) & ~(size_t)255;
    return p;
  };
  uint16_t* hB = (uint16_t*)alloc((size_t)N_NODES * IN_F * 2);     // 12.8 MB
  uint16_t* haggB = (uint16_t*)alloc((size_t)N_NODES * HID_F * 2); // 12.8 MB
  uint16_t* QwB = (uint16_t*)alloc((size_t)HID_F * IN_F * 2);
  uint16_t* WwB = (uint16_t*)alloc((size_t)OUT_F * CAT_F * 2);
  float* wsumG = (float*)alloc((size_t)N_NODES * 4);               // 200 KB
  int* gcnt = (int*)alloc((size_t)NREG * 4);                       // 784 B
  int2* recG = (int2*)alloc((size_t)NREG * RCAP * 8);              // 7.2 MB
  // total ~33 MB

  const int CONV_BLOCKS = ((N_NODES * IN_F + HID_F * IN_F + OUT_F * CAT_F) / 4 + 255) / 256;
  hipMemsetAsync(gcnt, 0, (size_t)NREG * 4, stream);
  prep_scatter_kernel<<<NB + CONV_BLOCKS, 256, 0, stream>>>(dst, src, ppr, gcnt, recG, h,
                                                            Qw, Ww, hB, QwB, WwB);
  agg_kernel<<<NBUCK, 256, 0, stream>>>(recG, gcnt, hB, haggB, wsumG);
  qgemm2_kernel<<<(NBUCK + 3) / 4, 256, 0, stream>>>(haggB, wsumG, hB, QwB, Qb, WwB, Wb,
                                                     out);
}

// Round 11
// 186.619 us; speedup vs baseline: 1.0873x; 1.0873x over previous
//
#include <hip/hip_runtime.h>
#include <stdint.h>

#define N_NODES 50000
#define N_EDGES 800000
#define IN_F 128
#define HID_F 128
#define OUT_F 128
#define CAT_F 256

#define NB 256       // edge partition blocks
#define CHUNK 3136   // edges per partition (int4-aligned; 256*3136 >= 800000)
#define NBUCK 3125   // 16-node buckets (50000/16 exact)
#define BCAP 384     // fixed per-bucket rec capacity (mean 256, +8 sigma)

typedef __bf16 bf16x8 __attribute__((ext_vector_type(8)));
typedef float f32x4 __attribute__((ext_vector_type(4)));

__device__ __forceinline__ uint32_t f2b(float f) {
  uint32_t u = __float_as_uint(f);
  return (u + 0x7fffu + ((u >> 16) & 1u)) >> 16;  // RNE
}

// ---- K1: fused  [0,NB): per-partition LDS histogram -> G row (block-major,
// coalesced write) | [NB,..): h/Qw/Ww -> bf16 convert.  (R5 verbatim)
__global__ void __launch_bounds__(256) prep_hist_kernel(
    const int* __restrict__ dst, int* __restrict__ G, const float* __restrict__ h,
    const float* __restrict__ Qw, const float* __restrict__ Ww, uint16_t* __restrict__ hB,
    uint16_t* __restrict__ QwB, uint16_t* __restrict__ WwB) {
  if (blockIdx.x < NB) {
    __shared__ int hist[NBUCK];  // 12.5 KB
    for (int k = threadIdx.x; k < NBUCK; k += 256) hist[k] = 0;
    __syncthreads();
    int b = blockIdx.x;
    int base = b * CHUNK;
    int end = (base + CHUNK < N_EDGES) ? (base + CHUNK) : N_EDGES;
    for (int i4 = base / 4 + threadIdx.x; i4 * 4 < end; i4 += 256) {
      int4 d4 = ((const int4*)dst)[i4];  // CHUNK,N_EDGES divisible by 4
      atomicAdd(&hist[d4.x >> 4], 1);
      atomicAdd(&hist[d4.y >> 4], 1);
      atomicAdd(&hist[d4.z >> 4], 1);
      atomicAdd(&hist[d4.w >> 4], 1);
    }
    __syncthreads();
    for (int k = threadIdx.x; k < NBUCK; k += 256) G[(size_t)b * NBUCK + k] = hist[k];
  } else {
    const int TOT4 = (N_NODES * IN_F + HID_F * IN_F + OUT_F * CAT_F) / 4;  // 1612288
    int i4 = (blockIdx.x - NB) * 256 + threadIdx.x;
    if (i4 >= TOT4) return;
    int base = i4 * 4;
    const float* srcp;
    uint16_t* dstp;
    int off;
    if (base < N_NODES * IN_F) {
      srcp = h; dstp = hB; off = base;
    } else if (base < N_NODES * IN_F + HID_F * IN_F) {
      srcp = Qw; dstp = QwB; off = base - N_NODES * IN_F;
    } else {
      srcp = Ww; dstp = WwB; off = base - N_NODES * IN_F - HID_F * IN_F;
    }
    float4 v = *(const float4*)(srcp + off);
    ushort4 o;
    o.x = (uint16_t)f2b(v.x); o.y = (uint16_t)f2b(v.y);
    o.z = (uint16_t)f2b(v.z); o.w = (uint16_t)f2b(v.w);
    *(ushort4*)(dstp + off) = o;
  }
}

// ---- K2: per-bucket exclusive scan over its NB=256 partition counts,
// IN-PLACE in block-major G; lane l covers partitions [4l,4l+4). Also emits
// cnt[k] = bucket total. (R5's colscan; Btot renamed cnt.) No base scan
// needed: rec is fixed-stride (bucket k base = k*BCAP).
__global__ void __launch_bounds__(256) colscan_kernel(int* __restrict__ G,
                                                      int* __restrict__ cnt) {
  int w = (blockIdx.x * 256 + (int)threadIdx.x) >> 6;  // bucket id
  if (w >= NBUCK) return;
  int lane = threadIdx.x & 63;
  int v0 = G[(size_t)(4 * lane + 0) * NBUCK + w];
  int v1 = G[(size_t)(4 * lane + 1) * NBUCK + w];
  int v2 = G[(size_t)(4 * lane + 2) * NBUCK + w];
  int v3 = G[(size_t)(4 * lane + 3) * NBUCK + w];
  int s = v0 + v1 + v2 + v3;
  int inc = s;
#pragma unroll
  for (int d = 1; d < 64; d <<= 1) {
    int x = __shfl_up(inc, d, 64);
    if (lane >= d) inc += x;
  }
  int exc = inc - s;
  G[(size_t)(4 * lane + 0) * NBUCK + w] = exc;
  G[(size_t)(4 * lane + 1) * NBUCK + w] = exc + v0;
  G[(size_t)(4 * lane + 2) * NBUCK + w] = exc + v0 + v1;
  G[(size_t)(4 * lane + 3) * NBUCK + w] = exc + v0 + v1 + v2;
  if (lane == 63) cnt[w] = inc;
}

// ---- K3: scatter via per-partition LDS cursors into FIXED-STRIDE bucket
// regions: cursor[k] = k*BCAP + within-bucket offset (deterministic, no
// returning global atomics anywhere in the pipeline -> no 300ns/op
// same-address floor). Record: x = src(20b) | local-node(4b)<<20; y = weight.
__global__ void __launch_bounds__(256) scatter_kernel(
    const int* __restrict__ dst, const int* __restrict__ src, const float* __restrict__ ppr,
    const int* __restrict__ G, int2* __restrict__ rec) {
  __shared__ int cursor[NBUCK];  // 12.5 KB
  int b = blockIdx.x;
  for (int k = threadIdx.x; k < NBUCK; k += 256)
    cursor[k] = k * BCAP + G[(size_t)b * NBUCK + k];
  __syncthreads();
  int base = b * CHUNK;
  int end = (base + CHUNK < N_EDGES) ? (base + CHUNK) : N_EDGES;
  for (int i4 = base / 4 + threadIdx.x; i4 * 4 < end; i4 += 256) {
    int4 d4 = ((const int4*)dst)[i4];
    int4 s4 = ((const int4*)src)[i4];
    float4 w4 = ((const float4*)ppr)[i4];
    int k, p;
    k = d4.x >> 4; p = atomicAdd(&cursor[k], 1);
    if (p < (k + 1) * BCAP) rec[p] = make_int2(s4.x | ((d4.x & 15) << 20), __float_as_int(w4.x));
    k = d4.y >> 4; p = atomicAdd(&cursor[k], 1);
    if (p < (k + 1) * BCAP) rec[p] = make_int2(s4.y | ((d4.y & 15) << 20), __float_as_int(w4.y));
    k = d4.z >> 4; p = atomicAdd(&cursor[k], 1);
    if (p < (k + 1) * BCAP) rec[p] = make_int2(s4.z | ((d4.z & 15) << 20), __float_as_int(w4.z));
    k = d4.w >> 4; p = atomicAdd(&cursor[k], 1);
    if (p < (k + 1) * BCAP) rec[p] = make_int2(s4.w | ((d4.w & 15) << 20), __float_as_int(w4.w));
  }
}

// ---- K4: fused aggregation + Q + GEMM2 (R6 verbatim except fixed-stride rec
// indexing). Block g (256 thr, 4 waves) owns 16 nodes. Q is linear:
// h_agg = safediv(sum w*h[src], sum w) @ Qw^T + Qb  (Qb gated by ws!=0).
__global__ void __launch_bounds__(256, 4) agg_gemm2_kernel(
    const int2* __restrict__ rec, const int* __restrict__ cnt,
    const uint16_t* __restrict__ hB, const uint16_t* __restrict__ QwB,
    const float* __restrict__ Qb, const uint16_t* __restrict__ WwB,
    const float* __restrict__ Wb, float* __restrict__ out) {
  __shared__ int2 srec[BCAP];     // 3.0 KB
  __shared__ uint4 hagg[16][17];  // raw aggregated h, bf16 (pad breaks conflicts)
  __shared__ uint4 hq2[16][17];   // Q-transformed agg, bf16
  __shared__ int hist[16];
  __shared__ int noff[17];
  __shared__ int cur[16];
  __shared__ float wsum[16];
  __shared__ float ssp[4][16];    // per-wave partial squared-norms
  int g = blockIdx.x;
  int t = threadIdx.x;
  if (t < 16) hist[t] = 0;
  __syncthreads();

  int len = cnt[g];
  len = (len < BCAP) ? len : BCAP;
  const int2* rbase = rec + (size_t)g * BCAP;

  // P1: load to registers + histogram (2*256 >= BCAP)
  int2 rc[2];
#pragma unroll
  for (int k = 0; k < 2; ++k) {
    int i = t + k * 256;
    if (i < len) {
      rc[k] = rbase[i];
      atomicAdd(&hist[rc[k].x >> 20], 1);
    }
  }
  __syncthreads();

  // P2: exclusive scan of 16 counters (lanes 0..15 of wave 0)
  if (t < 16) {
    int v = hist[t];
    int inc = v;
#pragma unroll
    for (int d = 1; d < 16; d <<= 1) {
      int x = __shfl_up(inc, d, 64);
      if (t >= d) inc += x;
    }
    noff[t] = inc - v;
    cur[t] = inc - v;
    if (t == 15) noff[16] = inc;
  }
  __syncthreads();

  // P3: scatter registers -> node-sorted LDS
#pragma unroll
  for (int k = 0; k < 2; ++k) {
    int i = t + k * 256;
    if (i < len) {
      int p = atomicAdd(&cur[rc[k].x >> 20], 1);
      srec[p] = rc[k];
    }
  }
  __syncthreads();

  // P4: sub-as-node aggregation of RAW h with 2-deep ping-pong prefetch.
  // 16 subs of 16 lanes; each sub owns 1 node (3125*16 = 50000 exactly).
  {
    int gs = t >> 4, c = t & 15;
    const uint4* hb4 = (const uint4*)hB;
    int nl = gs;
    int nbeg = noff[nl], nend = noff[nl + 1];
    int last = nend - 1;
    float a[8];
#pragma unroll
    for (int j = 0; j < 8; ++j) a[j] = 0.f;
    float ws = 0.f;

    int2 rrA[4], rrB[4];
    uint4 uA[4], uB[4];

#define LOADB(E0, RR, UU)                                         \
  {                                                               \
    _Pragma("unroll") for (int j = 0; j < 4; ++j) {               \
      int i = (E0) + j;                                           \
      RR[j] = srec[(i < last) ? i : last];                        \
    }                                                             \
    _Pragma("unroll") for (int j = 0; j < 4; ++j)                 \
        UU[j] = hb4[(size_t)(RR[j].x & 0xFFFFF) * 16 + c];        \
  }

#define CONSB(E0, RR, UU)                                           \
  {                                                                 \
    _Pragma("unroll") for (int j = 0; j < 4; ++j) {                 \
      float w = ((E0) + j < nend) ? __int_as_float(RR[j].y) : 0.f;  \
      ws += w;                                                      \
      uint32_t x;                                                   \
      x = UU[j].x;                                                  \
      a[0] += w * __uint_as_float(x << 16);                         \
      a[1] += w * __uint_as_float(x & 0xffff0000u);                 \
      x = UU[j].y;                                                  \
      a[2] += w * __uint_as_float(x << 16);                         \
      a[3] += w * __uint_as_float(x & 0xffff0000u);                 \
      x = UU[j].z;                                                  \
      a[4] += w * __uint_as_float(x << 16);                         \
      a[5] += w * __uint_as_float(x & 0xffff0000u);                 \
      x = UU[j].w;                                                  \
      a[6] += w * __uint_as_float(x << 16);                         \
      a[7] += w * __uint_as_float(x & 0xffff0000u);                 \
    }                                                               \
  }

    int e = nbeg;
    if (e < nend) {
      LOADB(e, rrA, uA);
      while (true) {
        int eB = e + 4;
        if (eB < nend) {
          LOADB(eB, rrB, uB);   // B in flight while A consumed
          CONSB(e, rrA, uA);
          int eA = eB + 4;
          if (eA < nend) {
            LOADB(eA, rrA, uA); // A in flight while B consumed
            CONSB(eB, rrB, uB);
            e = eA;
          } else {
            CONSB(eB, rrB, uB);
            break;
          }
        } else {
          CONSB(e, rrA, uA);
          break;
        }
      }
    }
#undef LOADB
#undef CONSB

    float dnm = (ws == 0.f) ? 1.f : ws;  // safediv
    float inv = 1.f / dnm;
    uint4 o;
    o.x = f2b(a[0] * inv) | (f2b(a[1] * inv) << 16);
    o.y = f2b(a[2] * inv) | (f2b(a[3] * inv) << 16);
    o.z = f2b(a[4] * inv) | (f2b(a[5] * inv) << 16);
    o.w = f2b(a[6] * inv) | (f2b(a[7] * inv) << 16);
    hagg[nl][c] = o;
    if (c == 0) wsum[nl] = ws;
  }
  __syncthreads();

  int lane = t & 63, wv = t >> 6;
  int r = lane & 15, qd = lane >> 4;

  // P4.5: hq2 = hagg @ Qw^T + Qb (Qb gated by ws!=0, matching safediv on an
  // empty node where the reference yields 0 not Qb). 8 col-tiles over 4 waves.
#pragma unroll
  for (int tq = 0; tq < 2; ++tq) {
    int tt = wv * 2 + tq;
    f32x4 acc = (f32x4){0.f, 0.f, 0.f, 0.f};
#pragma unroll
    for (int kt = 0; kt < 4; ++kt) {
      bf16x8 av = *(const bf16x8*)&hagg[r][kt * 4 + qd];
      bf16x8 b = *(const bf16x8*)(QwB + (tt * 16 + r) * IN_F + kt * 32 + qd * 8);
      acc = __builtin_amdgcn_mfma_f32_16x16x32_bf16(av, b, acc, 0, 0, 0);
    }
    float qb = Qb[tt * 16 + r];
#pragma unroll
    for (int rr2 = 0; rr2 < 4; ++rr2) {
      int row = qd * 4 + rr2;
      float flag = (wsum[row] != 0.f) ? 1.f : 0.f;
      ((uint16_t*)&hq2[row][0])[tt * 16 + r] = (uint16_t)f2b(acc[rr2] + qb * flag);
    }
  }
  __syncthreads();

  // P5: gemm2 out = leaky([hB | hq2] @ Ww^T + Wb), L2-normalized per row.
  // 8 col-tiles over 4 waves; norm cross-wave-reduced via ssp.
  int row0 = g * 16;
  f32x4 acc2[2];
  acc2[0] = (f32x4){0.f, 0.f, 0.f, 0.f};
  acc2[1] = (f32x4){0.f, 0.f, 0.f, 0.f};
  const uint16_t* aRow = hB + (size_t)(row0 + r) * IN_F + qd * 8;
#pragma unroll
  for (int kt = 0; kt < 8; ++kt) {
    bf16x8 av;
    if (kt < 4) {
      av = *(const bf16x8*)(aRow + kt * 32);
    } else {
      av = *(const bf16x8*)&hq2[r][(kt - 4) * 4 + qd];
    }
#pragma unroll
    for (int tq = 0; tq < 2; ++tq) {
      int tt = wv * 2 + tq;
      bf16x8 b = *(const bf16x8*)(WwB + (tt * 16 + r) * CAT_F + kt * 32 + qd * 8);
      acc2[tq] = __builtin_amdgcn_mfma_f32_16x16x32_bf16(av, b, acc2[tq], 0, 0, 0);
    }
  }
  float lv[2][4];
  float ss[4] = {0.f, 0.f, 0.f, 0.f};
#pragma unroll
  for (int tq = 0; tq < 2; ++tq) {
    int tt = wv * 2 + tq;
    float wb = Wb[tt * 16 + r];
#pragma unroll
    for (int rr2 = 0; rr2 < 4; ++rr2) {
      float v = acc2[tq][rr2] + wb;
      v = (v >= 0.f) ? v : 0.01f * v;
      lv[tq][rr2] = v;
      ss[rr2] += v * v;
    }
  }
#pragma unroll
  for (int rr2 = 0; rr2 < 4; ++rr2) {
    float s = ss[rr2];
    s += __shfl_xor(s, 1);
    s += __shfl_xor(s, 2);
    s += __shfl_xor(s, 4);
    s += __shfl_xor(s, 8);
    ss[rr2] = s;  // sum over this wave's 32 cols, all lanes hold it
  }
  if (r == 0) {
#pragma unroll
    for (int rr2 = 0; rr2 < 4; ++rr2) ssp[wv][qd * 4 + rr2] = ss[rr2];
  }
  __syncthreads();
#pragma unroll
  for (int rr2 = 0; rr2 < 4; ++rr2) {
    int row = qd * 4 + rr2;
    float tot = ssp[0][row] + ssp[1][row] + ssp[2][row] + ssp[3][row];
    float nr = sqrtf(tot);
    float inv = (nr == 0.f) ? 1.f : (1.f / nr);
    float* orow = out + (size_t)(row0 + row) * OUT_F;
#pragma unroll
    for (int tq = 0; tq < 2; ++tq) {
      int tt = wv * 2 + tq;
      orow[tt * 16 + r] = lv[tq][rr2] * inv;
    }
  }
}

extern "C" void kernel_launch(void* const* d_in, const int* in_sizes, int n_in,
                              void* d_out, int out_size, void* d_ws, size_t ws_size,
                              hipStream_t stream) {
  const float* h = (const float*)d_in[0];
  const float* ppr = (const float*)d_in[1];
  const float* Qw = (const float*)d_in[2];
  const float* Qb = (const float*)d_in[3];
  const float* Ww = (const float*)d_in[4];
  const float* Wb = (const float*)d_in[5];
  const int* src = (const int*)d_in[6];
  const int* dst = (const int*)d_in[7];
  float* out = (float*)d_out;

  char* ws = (char*)d_ws;
  size_t o = 0;
  auto alloc = [&](size_t bytes) {
    void* p = ws + o;
    o = (o + bytes + 255) & ~(size_t)255;
    return p;
  };
  uint16_t* hB = (uint16_t*)alloc((size_t)N_NODES * IN_F * 2);  // 12.8 MB
  uint16_t* QwB = (uint16_t*)alloc((size_t)HID_F * IN_F * 2);
  uint16_t* WwB = (uint16_t*)alloc((size_t)OUT_F * CAT_F * 2);
  int* G = (int*)alloc((size_t)NB * NBUCK * 4);       // 3.2 MB, block-major
  int* cnt = (int*)alloc((size_t)NBUCK * 4);          // 12.5 KB
  int2* rec = (int2*)alloc((size_t)NBUCK * BCAP * 8); // 9.6 MB
  // total ~26 MB; no memset needed (G/cnt fully written each call)

  const int CONV_BLOCKS = ((N_NODES * IN_F + HID_F * IN_F + OUT_F * CAT_F) / 4 + 255) / 256;
  prep_hist_kernel<<<NB + CONV_BLOCKS, 256, 0, stream>>>(dst, G, h, Qw, Ww, hB, QwB, WwB);
  colscan_kernel<<<(NBUCK + 3) / 4, 256, 0, stream>>>(G, cnt);
  scatter_kernel<<<NB, 256, 0, stream>>>(dst, src, ppr, G, rec);
  agg_gemm2_kernel<<<NBUCK, 256, 0, stream>>>(rec, cnt, hB, QwB, Qb, WwB, Wb, out);
}